// Round 10
// baseline (157.550 us; speedup 1.0000x reference)
//
#include <hip/hip_runtime.h>
#include <math.h>

// Shapes fixed by the reference: x [B=16, C=512, N=4096] fp32.
constexpr int B  = 16;
constexpr int C  = 512;
constexpr int N  = 4096;
constexpr int CR = 128;   // C/4
constexpr int NT = 128;   // n-tile per GEMM block
constexpr int KC = 64;    // c-chunk (fallback path)

typedef __attribute__((ext_vector_type(8))) short bf16x8;
typedef __attribute__((ext_vector_type(4))) float f32x4;

__device__ __forceinline__ float sigmoidf_(float v) {
    return 1.0f / (1.0f + __expf(-v));
}
// fp32 -> bf16 round-to-nearest-even
__device__ __forceinline__ unsigned f2bf(float f) {
    unsigned u = __float_as_uint(f);
    u += 0x7fffu + ((u >> 16) & 1u);
    return u >> 16;
}

#define LGKM_BARRIER() do {                                   \
    asm volatile("s_waitcnt lgkmcnt(0)" ::: "memory");        \
    __builtin_amdgcn_s_barrier();                             \
    asm volatile("" ::: "memory");                            \
} while (0)

// ---------------------------------------------------------------------------
// k_pre: (blocks 0..511)  pool 16 rows/block (contiguous read) and, if
//        do_xbt, emit xbT[b][c/16][n][16] bf16 via an LDS 16x256 transpose
//        (contiguous 8 KB writes).  (blocks 512..543) BN-fold w3 -> w3f
//        (MFMA A-fragment lane order) + bias2.
// ---------------------------------------------------------------------------
__global__ __launch_bounds__(256) void k_pre(
    const float* __restrict__ x, float* __restrict__ pooled,
    const float* __restrict__ w3, const float* __restrict__ b3,
    const float* __restrict__ gamma, const float* __restrict__ beta,
    const float* __restrict__ mean, const float* __restrict__ var,
    unsigned short* __restrict__ w3f, float* __restrict__ bias2,
    unsigned short* __restrict__ xbT, int do_xbt)
{
    if (blockIdx.x < 512) {
        __shared__ float tr[16][256];
        const int g = blockIdx.x, b = g >> 5, c16 = g & 31;
        const int t = threadIdx.x, lane = t & 63, w = t >> 6;
        const float4* xr = (const float4*)(x + ((size_t)b * C + c16 * 16) * N);
        float ps[4] = {0.f, 0.f, 0.f, 0.f};
        for (int ch = 0; ch < 16; ++ch) {
            float4 v[4];
            #pragma unroll
            for (int i = 0; i < 4; ++i) {
                int r = i * 4 + w;
                v[i] = xr[(size_t)r * 1024 + ch * 64 + lane];
                ps[i] += v[i].x + v[i].y + v[i].z + v[i].w;
            }
            if (do_xbt) {
                #pragma unroll
                for (int i = 0; i < 4; ++i)
                    *(float4*)&tr[i * 4 + w][lane * 4] = v[i];
                __syncthreads();
                int n = ch * 256 + t;
                unsigned q[8];
                #pragma unroll
                for (int h = 0; h < 8; ++h)
                    q[h] = f2bf(tr[2 * h][t]) | (f2bf(tr[2 * h + 1][t]) << 16);
                size_t off = (((size_t)b * 32 + c16) * 4096 + n) * 16;  // shorts
                *(uint4*)(xbT + off)     = make_uint4(q[0], q[1], q[2], q[3]);
                *(uint4*)(xbT + off + 8) = make_uint4(q[4], q[5], q[6], q[7]);
                __syncthreads();
            }
        }
        #pragma unroll
        for (int i = 0; i < 4; ++i) {
            #pragma unroll
            for (int o = 32; o; o >>= 1) ps[i] += __shfl_xor(ps[i], o, 64);
        }
        if (lane == 0) {
            #pragma unroll
            for (int i = 0; i < 4; ++i)
                pooled[b * C + c16 * 16 + i * 4 + w] = ps[i] * (1.0f / N);
        }
    } else {
        int idx  = (blockIdx.x - 512) * 256 + threadIdx.x;   // 0..8191
        int g    = idx >> 6;
        int lane = idx & 63;
        int ck   = g >> 4;
        int kk   = (g >> 3) & 1;
        int ob   = g & 7;
        int o    = ob * 16 + (lane & 15);
        int c    = ck * 64 + kk * 32 + (lane >> 4) * 8;
        float inv = gamma[o] * rsqrtf(var[o] + 1e-5f);
        float4 a  = *(const float4*)(w3 + o * C + c);
        float4 bq = *(const float4*)(w3 + o * C + c + 4);
        unsigned r0 = f2bf(a.x * inv)  | (f2bf(a.y * inv) << 16);
        unsigned r1 = f2bf(a.z * inv)  | (f2bf(a.w * inv) << 16);
        unsigned r2 = f2bf(bq.x * inv) | (f2bf(bq.y * inv) << 16);
        unsigned r3 = f2bf(bq.z * inv) | (f2bf(bq.w * inv) << 16);
        *(uint4*)((char*)w3f + (size_t)idx * 16) = make_uint4(r0, r1, r2, r3);
        if (idx < CR) {
            float iv = gamma[idx] * rsqrtf(var[idx] + 1e-5f);
            bias2[idx] = b3[idx] * iv + beta[idx] - mean[idx] * iv;
        }
    }
}

// ---------------------------------------------------------------------------
// k_ca: channel-attention MLP + per-batch ca-fold into the fragment weights.
// ---------------------------------------------------------------------------
__global__ __launch_bounds__(256) void k_ca(
    const float* __restrict__ pooled,
    const float* __restrict__ w1, const float* __restrict__ b1,
    const float* __restrict__ w2, const float* __restrict__ b2,
    const unsigned short* __restrict__ w3f,
    float* __restrict__ ca, unsigned short* __restrict__ w3b)
{
    __shared__ float ps[C];
    __shared__ float hs[CR];
    __shared__ float ca_s[C];
    int b = blockIdx.x, t = threadIdx.x;
    ps[t] = pooled[b * C + t];
    ps[t + 256] = pooled[b * C + t + 256];
    __syncthreads();

    if (t < CR) {
        float acc = b1[t];
        const float4* wr = (const float4*)(w1 + t * C);
        const float4* pr = (const float4*)ps;
        #pragma unroll 4
        for (int i = 0; i < C / 4; ++i) {
            float4 wv = wr[i], pv = pr[i];
            acc += wv.x * pv.x + wv.y * pv.y + wv.z * pv.z + wv.w * pv.w;
        }
        hs[t] = fmaxf(acc, 0.f);
    }
    __syncthreads();

    #pragma unroll
    for (int k = 0; k < 2; ++k) {
        int c2 = t + k * 256;
        float a = b2[c2];
        const float4* w2r = (const float4*)(w2 + c2 * CR);
        const float4* hr  = (const float4*)hs;
        #pragma unroll 4
        for (int i = 0; i < CR / 4; ++i) {
            float4 wv = w2r[i], hv = hr[i];
            a += wv.x * hv.x + wv.y * hv.y + wv.z * hv.z + wv.w * hv.w;
        }
        float cav = sigmoidf_(a);
        ca_s[c2] = cav;
        ca[b * C + c2] = cav;
    }
    __syncthreads();

    #pragma unroll 4
    for (int j = 0; j < 32; ++j) {
        int i    = j * 256 + t;
        int g    = i >> 6;
        int lane = i & 63;
        int ck   = g >> 4;
        int kk   = (g >> 3) & 1;
        int c0   = ck * 64 + kk * 32 + ((lane >> 4) << 3);
        uint4 wv = *(const uint4*)((const char*)w3f + (size_t)i * 16);
        const float* cb = &ca_s[c0];
        uint4 ov;
        {
            float lo = __uint_as_float(wv.x << 16), hi = __uint_as_float(wv.x & 0xffff0000u);
            ov.x = f2bf(lo * cb[0]) | (f2bf(hi * cb[1]) << 16);
        }
        {
            float lo = __uint_as_float(wv.y << 16), hi = __uint_as_float(wv.y & 0xffff0000u);
            ov.y = f2bf(lo * cb[2]) | (f2bf(hi * cb[3]) << 16);
        }
        {
            float lo = __uint_as_float(wv.z << 16), hi = __uint_as_float(wv.z & 0xffff0000u);
            ov.z = f2bf(lo * cb[4]) | (f2bf(hi * cb[5]) << 16);
        }
        {
            float lo = __uint_as_float(wv.w << 16), hi = __uint_as_float(wv.w & 0xffff0000u);
            ov.w = f2bf(lo * cb[6]) | (f2bf(hi * cb[7]) << 16);
        }
        *(uint4*)((char*)w3b + ((size_t)b * 8192 + i) * 16) = ov;
    }
}

// ---------------------------------------------------------------------------
// k_gemm_out: per (b, 128-col n-tile), 512 thr / 8 waves.  NO K-loop LDS or
// barriers: A-frags from w3b (ca folded, L2-hot), B-frags DIRECT from xbT
// (bf16, pre-transposed, L3-hot; wave = 2x512B contiguous segments/inst).
//   sa[n] = sigmoid(sum_o w4[o]*relu(h2+bias2)+b4);  out = x*(1+ca*sa)
// ---------------------------------------------------------------------------
__global__ __launch_bounds__(512, 4) void k_gemm_out(
    const float* __restrict__ x, const unsigned short* __restrict__ xbT,
    const unsigned short* __restrict__ w3b, const float* __restrict__ ca,
    const float* __restrict__ bias2, const float* __restrict__ w4,
    const float* __restrict__ b4, float* __restrict__ out)
{
    __shared__ float red[4][NT];
    __shared__ __align__(16) float sa_s[NT];
    __shared__ float ca_s[C];
    __shared__ float bias2_s[CR];
    __shared__ float w4_s[CR];

    const int t    = threadIdx.x;
    const int lane = t & 63;
    const int w    = t >> 6;
    const int b    = blockIdx.y;
    const int n0   = blockIdx.x * NT;
    const int wo   = (w & 3) * 32;
    const int wn   = (w >> 2) * 64;
    const int ob0  = (w & 3) * 2;

    if (t < 256) { ca_s[t] = ca[b * C + t]; ca_s[t + 256] = ca[b * C + t + 256]; }
    if (t < CR)  { bias2_s[t] = bias2[t]; w4_s[t] = w4[t]; }

    // per-lane B base in shorts: n-row = n0+wn+(lane&15), c16 sel by lane>>5,
    // 8-short col offset by (lane>>4)&1
    const int csel = lane >> 4;          // 0..3
    const unsigned short* bbase = xbT
        + ((size_t)b * 32 + (csel >> 1)) * 65536
        + (size_t)(n0 + wn + (lane & 15)) * 16
        + (csel & 1) * 8;
    const char* wb = (const char*)w3b + (size_t)b * 131072 + (size_t)lane * 16;

    f32x4 acc[2][4];
    #pragma unroll
    for (int i = 0; i < 2; ++i)
        #pragma unroll
        for (int j = 0; j < 4; ++j) acc[i][j] = (f32x4)0.f;

    #pragma unroll
    for (int ck = 0; ck < 8; ++ck) {
        bf16x8 af[2][2];
        #pragma unroll
        for (int kk = 0; kk < 2; ++kk)
            #pragma unroll
            for (int i = 0; i < 2; ++i)
                af[kk][i] = *(const bf16x8*)(wb + (size_t)(ck * 16 + kk * 8 + ob0 + i) * 1024);
        bf16x8 bfv[2][4];
        #pragma unroll
        for (int kk = 0; kk < 2; ++kk)
            #pragma unroll
            for (int j = 0; j < 4; ++j)
                bfv[kk][j] = *(const bf16x8*)(bbase + (size_t)(ck * 4 + kk * 2) * 65536 + j * 256);
        #pragma unroll
        for (int kk = 0; kk < 2; ++kk)
            #pragma unroll
            for (int i = 0; i < 2; ++i)
                #pragma unroll
                for (int j = 0; j < 4; ++j)
                    acc[i][j] = __builtin_amdgcn_mfma_f32_16x16x32_bf16(af[kk][i], bfv[kk][j], acc[i][j], 0, 0, 0);
    }

    // ---- sa: per-lane partial over this wave's 32 o's, then cross-lane.
    #pragma unroll
    for (int j = 0; j < 4; ++j) {
        float p = 0.f;
        #pragma unroll
        for (int i = 0; i < 2; ++i) {
            #pragma unroll
            for (int r = 0; r < 4; ++r) {
                int o = wo + i * 16 + ((lane >> 4) << 2) + r;
                p = fmaf(w4_s[o], fmaxf(acc[i][j][r] + bias2_s[o], 0.f), p);
            }
        }
        p += __shfl_xor(p, 16, 64);
        p += __shfl_xor(p, 32, 64);
        if (lane < 16) red[w & 3][wn + j * 16 + lane] = p;
    }
    __syncthreads();
    if (t < NT)
        sa_s[t] = sigmoidf_(red[0][t] + red[1][t] + red[2][t] + red[3][t] + b4[0]);
    __syncthreads();

    // ---- epilogue: out = x * (1 + ca[c]*sa[n]); fp32 x read (L3-hot)
    const size_t xbase = (size_t)b * C * N + n0;
    #pragma unroll 4
    for (int it = 0; it < 32; ++it) {
        int f4 = it * 512 + t;          // 0..16383
        int c  = f4 >> 5;
        int n4 = f4 & 31;
        size_t off = xbase + (size_t)c * N + n4 * 4;
        float4 v = *(const float4*)(x + off);
        float cav = ca_s[c];
        float4 sv = *(const float4*)&sa_s[n4 * 4];
        float4 o4;
        o4.x = v.x * fmaf(cav, sv.x, 1.0f);
        o4.y = v.y * fmaf(cav, sv.y, 1.0f);
        o4.z = v.z * fmaf(cav, sv.z, 1.0f);
        o4.w = v.w * fmaf(cav, sv.w, 1.0f);
        *(float4*)(out + off) = o4;
    }
}

// ---------------------------------------------------------------------------
// k_main_fb: round-8 fused fallback (used only if ws_size can't hold xbT).
// ---------------------------------------------------------------------------
__global__ __launch_bounds__(512, 2) void k_main_fb(
    const float* __restrict__ x, const float* __restrict__ ca,
    const unsigned short* __restrict__ w3f, const float* __restrict__ bias2,
    const float* __restrict__ w4, const float* __restrict__ b4,
    float* __restrict__ out)
{
    __shared__ __align__(16) short lds_x[2][NT * KC];
    __shared__ float ca_s[C];
    __shared__ __align__(16) float sa_s[NT];
    __shared__ float red[4][NT];
    __shared__ float bias2_s[CR];
    __shared__ float w4_s[CR];

    const int t    = threadIdx.x;
    const int lane = t & 63;
    const int w    = t >> 6;
    const int b    = blockIdx.y;
    const int n0   = blockIdx.x * NT;
    const int wo   = (w & 3) * 32;
    const int wn   = (w >> 2) * 64;
    const int ob0  = (w & 3) * 2;

    const size_t xbase = (size_t)b * C * N + n0;
    const int ng = t & 63;
    const int cg = t >> 6;

    ca_s[t] = ca[b * C + t];
    if (t < CR) { bias2_s[t] = bias2[t]; w4_s[t] = w4[t]; }

    float2 xva[8], xvb[8];

#define LOADX(dst, CK) do { const int c0_ = (CK) * KC;                         \
    _Pragma("unroll") for (int ci = 0; ci < 8; ++ci)                           \
        dst[ci] = *(const float2*)(x + xbase + (size_t)(c0_ + cg * 8 + ci) * N + 2 * ng); \
} while (0)
#define CONVERT_WRITE(src, CK, BUF) do { const int c0_ = (CK) * KC;            \
    unsigned q0[4], q1[4];                                                     \
    _Pragma("unroll") for (int h = 0; h < 4; ++h) {                            \
        float s0 = ca_s[c0_ + cg * 8 + 2 * h];                                 \
        float s1 = ca_s[c0_ + cg * 8 + 2 * h + 1];                             \
        q0[h] = f2bf(src[2 * h].x * s0) | (f2bf(src[2 * h + 1].x * s1) << 16); \
        q1[h] = f2bf(src[2 * h].y * s0) | (f2bf(src[2 * h + 1].y * s1) << 16); \
    }                                                                          \
    int nl0 = 2 * ng, nl1 = 2 * ng + 1;                                        \
    int a0 = (nl0 * 128 + cg * 16) ^ ((nl0 & 7) << 4);                         \
    int a1 = (nl1 * 128 + cg * 16) ^ ((nl1 & 7) << 4);                         \
    *(uint4*)((char*)lds_x[BUF] + a0) = make_uint4(q0[0], q0[1], q0[2], q0[3]);\
    *(uint4*)((char*)lds_x[BUF] + a1) = make_uint4(q1[0], q1[1], q1[2], q1[3]);\
} while (0)

    LOADX(xva, 0);
    LOADX(xvb, 1);
    LGKM_BARRIER();
    CONVERT_WRITE(xva, 0, 0);

    f32x4 acc[2][4];
    #pragma unroll
    for (int i = 0; i < 2; ++i)
        #pragma unroll
        for (int j = 0; j < 4; ++j) acc[i][j] = (f32x4)0.f;

    const char* wf = (const char*)w3f;

    #pragma unroll
    for (int ck = 0; ck < 8; ++ck) {
        if (ck < 6) { if (ck & 1) LOADX(xvb, ck + 2); else LOADX(xva, ck + 2); }
        LGKM_BARRIER();
        #pragma unroll
        for (int kk = 0; kk < 2; ++kk) {
            bf16x8 af[2];
            #pragma unroll
            for (int i = 0; i < 2; ++i) {
                int g = ck * 16 + kk * 8 + ob0 + i;
                af[i] = *(const bf16x8*)(wf + (size_t)(g * 64 + lane) * 16);
            }
            bf16x8 bfr[4];
            #pragma unroll
            for (int j = 0; j < 4; ++j) {
                int br = wn + j * 16 + (lane & 15);
                int bb = (br * 128 + kk * 64 + (lane >> 4) * 16) ^ ((br & 7) << 4);
                bfr[j] = *(const bf16x8*)((const char*)lds_x[ck & 1] + bb);
            }
            #pragma unroll
            for (int i = 0; i < 2; ++i)
                #pragma unroll
                for (int j = 0; j < 4; ++j)
                    acc[i][j] = __builtin_amdgcn_mfma_f32_16x16x32_bf16(af[i], bfr[j], acc[i][j], 0, 0, 0);
        }
        if (ck < 7) { if (ck & 1) CONVERT_WRITE(xva, ck + 1, 0); else CONVERT_WRITE(xvb, ck + 1, 1); }
    }
#undef LOADX
#undef CONVERT_WRITE

    #pragma unroll
    for (int j = 0; j < 4; ++j) {
        float p = 0.f;
        #pragma unroll
        for (int i = 0; i < 2; ++i) {
            #pragma unroll
            for (int r = 0; r < 4; ++r) {
                int o = wo + i * 16 + ((lane >> 4) << 2) + r;
                p = fmaf(w4_s[o], fmaxf(acc[i][j][r] + bias2_s[o], 0.f), p);
            }
        }
        p += __shfl_xor(p, 16, 64);
        p += __shfl_xor(p, 32, 64);
        if (lane < 16) red[w & 3][wn + j * 16 + lane] = p;
    }
    __syncthreads();
    if (t < NT) sa_s[t] = sigmoidf_(red[0][t] + red[1][t] + red[2][t] + red[3][t] + b4[0]);
    __syncthreads();

    #pragma unroll 4
    for (int it = 0; it < 32; ++it) {
        int f4 = it * 512 + t;
        int c  = f4 >> 5;
        int n4 = f4 & 31;
        size_t off = xbase + (size_t)c * N + n4 * 4;
        float4 v = *(const float4*)(x + off);
        float cav = ca_s[c];
        float4 sv = *(const float4*)&sa_s[n4 * 4];
        float4 o4;
        o4.x = v.x * fmaf(cav, sv.x, 1.0f);
        o4.y = v.y * fmaf(cav, sv.y, 1.0f);
        o4.z = v.z * fmaf(cav, sv.z, 1.0f);
        o4.w = v.w * fmaf(cav, sv.w, 1.0f);
        *(float4*)(out + off) = o4;
    }
}

extern "C" void kernel_launch(void* const* d_in, const int* in_sizes, int n_in,
                              void* d_out, int out_size, void* d_ws, size_t ws_size,
                              hipStream_t stream)
{
    const float* x   = (const float*)d_in[0];
    const float* w1  = (const float*)d_in[1];
    const float* b1  = (const float*)d_in[2];
    const float* w2  = (const float*)d_in[3];
    const float* b2  = (const float*)d_in[4];
    const float* w3  = (const float*)d_in[5];
    const float* b3  = (const float*)d_in[6];
    const float* g   = (const float*)d_in[7];
    const float* be  = (const float*)d_in[8];
    const float* mn  = (const float*)d_in[9];
    const float* vr  = (const float*)d_in[10];
    const float* w4  = (const float*)d_in[11];
    const float* b4  = (const float*)d_in[12];
    float* out = (float*)d_out;

    float* ws     = (float*)d_ws;
    float* pooled = ws;                                   // 8192 floats
    float* ca     = ws + 8192;                            // 8192 floats
    float* bias2  = ws + 16384;                           // 128 floats (+pad)
    unsigned short* w3f = (unsigned short*)(ws + 16640);  // 128 KB
    unsigned short* w3b = (unsigned short*)(ws + 49408);  // 2 MB
    unsigned short* xbT = (unsigned short*)(ws + 573696); // 64 MB bf16

    const size_t need = (size_t)573696 * 4 + (size_t)B * C * N * 2;
    const int use_xbt = (ws_size >= need) ? 1 : 0;

    k_pre<<<512 + 32, 256, 0, stream>>>(x, pooled, w3, b3, g, be, mn, vr,
                                        w3f, bias2, xbT, use_xbt);
    k_ca<<<B, 256, 0, stream>>>(pooled, w1, b1, w2, b2, w3f, ca, w3b);
    dim3 g3(N / NT, B);
    if (use_xbt)
        k_gemm_out<<<g3, 512, 0, stream>>>(x, xbT, w3b, ca, bias2, w4, b4, out);
    else
        k_main_fb<<<g3, 512, 0, stream>>>(x, ca, w3f, bias2, w4, b4, out);
}

// Round 11
// 124.605 us; speedup vs baseline: 1.2644x; 1.2644x over previous
//
#include <hip/hip_runtime.h>
#include <math.h>

// Shapes fixed by the reference: x [B=16, C=512, N=4096] fp32.
constexpr int B  = 16;
constexpr int C  = 512;
constexpr int N  = 4096;
constexpr int CR = 128;   // C/4
constexpr int NT = 128;   // n-tile per k_gemm block
constexpr int KC = 64;    // c-chunk per staging step

typedef __attribute__((ext_vector_type(8))) short bf16x8;
typedef __attribute__((ext_vector_type(4))) float f32x4;

__device__ __forceinline__ float sigmoidf_(float v) {
    return 1.0f / (1.0f + __expf(-v));
}
// fp32 -> bf16 round-to-nearest-even
__device__ __forceinline__ unsigned f2bf(float f) {
    unsigned u = __float_as_uint(f);
    u += 0x7fffu + ((u >> 16) & 1u);
    return u >> 16;
}

// lgkmcnt(0) + raw barrier: LDS writes visible WITHOUT draining vmcnt.
#define LGKM_BARRIER() do {                                   \
    asm volatile("s_waitcnt lgkmcnt(0)" ::: "memory");        \
    __builtin_amdgcn_s_barrier();                             \
    asm volatile("" ::: "memory");                            \
} while (0)

// ---------------------------------------------------------------------------
// k_pre: (blocks 0..2047)  pooled[b][c] = mean_n x[b][c][n]  (contiguous)
//        (blocks 2048..2079) BN-fold w3 -> bf16 MFMA A-fragment order (w3f)
//        + bias2.
// ---------------------------------------------------------------------------
__global__ __launch_bounds__(256) void k_pre(
    const float* __restrict__ x, float* __restrict__ pooled,
    const float* __restrict__ w3, const float* __restrict__ b3,
    const float* __restrict__ gamma, const float* __restrict__ beta,
    const float* __restrict__ mean, const float* __restrict__ var,
    unsigned short* __restrict__ w3f, float* __restrict__ bias2)
{
    if (blockIdx.x < 2048) {
        int w    = threadIdx.x >> 6;
        int lane = threadIdx.x & 63;
        int row  = blockIdx.x * 4 + w;              // b*C + c
        const float4* xr = (const float4*)(x + (size_t)row * N);
        float s = 0.f;
        #pragma unroll
        for (int i = 0; i < 16; ++i) {
            float4 v = xr[i * 64 + lane];
            s += v.x + v.y + v.z + v.w;
        }
        #pragma unroll
        for (int off = 32; off; off >>= 1) s += __shfl_xor(s, off, 64);
        if (lane == 0) pooled[row] = s * (1.0f / N);
    } else {
        int idx  = (blockIdx.x - 2048) * 256 + threadIdx.x;  // 0..8191
        int g    = idx >> 6;          // fragment group 0..127
        int lane = idx & 63;
        int ck   = g >> 4;
        int kk   = (g >> 3) & 1;
        int ob   = g & 7;
        int o    = ob * 16 + (lane & 15);
        int c    = ck * 64 + kk * 32 + (lane >> 4) * 8;
        float inv = gamma[o] * rsqrtf(var[o] + 1e-5f);
        float4 a  = *(const float4*)(w3 + o * C + c);
        float4 bq = *(const float4*)(w3 + o * C + c + 4);
        unsigned r0 = f2bf(a.x * inv)  | (f2bf(a.y * inv) << 16);
        unsigned r1 = f2bf(a.z * inv)  | (f2bf(a.w * inv) << 16);
        unsigned r2 = f2bf(bq.x * inv) | (f2bf(bq.y * inv) << 16);
        unsigned r3 = f2bf(bq.z * inv) | (f2bf(bq.w * inv) << 16);
        *(uint4*)((char*)w3f + (size_t)idx * 16) = make_uint4(r0, r1, r2, r3);
        if (idx < CR) {
            float iv = gamma[idx] * rsqrtf(var[idx] + 1e-5f);
            bias2[idx] = b3[idx] * iv + beta[idx] - mean[idx] * iv;
        }
    }
}

// ---------------------------------------------------------------------------
// k_ca: channel-attention MLP + per-batch ca-fold into the fragment weights.
//   h  = relu(pooled @ w1^T + b1); ca = sigmoid(h @ w2^T + b2)
//   w3b[b][i] = bf16( fp32(w3f[i]) * ca[c(i)] )   (2 MB total, L2-hot)
// ---------------------------------------------------------------------------
__global__ __launch_bounds__(256) void k_ca(
    const float* __restrict__ pooled,
    const float* __restrict__ w1, const float* __restrict__ b1,
    const float* __restrict__ w2, const float* __restrict__ b2,
    const unsigned short* __restrict__ w3f,
    float* __restrict__ ca, unsigned short* __restrict__ w3b)
{
    __shared__ float ps[C];
    __shared__ float hs[CR];
    __shared__ float ca_s[C];
    int b = blockIdx.x, t = threadIdx.x;
    ps[t] = pooled[b * C + t];
    ps[t + 256] = pooled[b * C + t + 256];
    __syncthreads();

    if (t < CR) {
        float acc = b1[t];
        const float4* wr = (const float4*)(w1 + t * C);
        const float4* pr = (const float4*)ps;
        #pragma unroll 4
        for (int i = 0; i < C / 4; ++i) {
            float4 wv = wr[i], pv = pr[i];
            acc += wv.x * pv.x + wv.y * pv.y + wv.z * pv.z + wv.w * pv.w;
        }
        hs[t] = fmaxf(acc, 0.f);
    }
    __syncthreads();

    #pragma unroll
    for (int k = 0; k < 2; ++k) {
        int c2 = t + k * 256;
        float a = b2[c2];
        const float4* w2r = (const float4*)(w2 + c2 * CR);
        const float4* hr  = (const float4*)hs;
        #pragma unroll 4
        for (int i = 0; i < CR / 4; ++i) {
            float4 wv = w2r[i], hv = hr[i];
            a += wv.x * hv.x + wv.y * hv.y + wv.z * hv.z + wv.w * hv.w;
        }
        float cav = sigmoidf_(a);
        ca_s[c2] = cav;
        ca[b * C + c2] = cav;
    }
    __syncthreads();

    #pragma unroll 4
    for (int j = 0; j < 32; ++j) {
        int i    = j * 256 + t;            // 0..8191, coalesced
        int g    = i >> 6;
        int lane = i & 63;
        int ck   = g >> 4;
        int kk   = (g >> 3) & 1;
        int c0   = ck * 64 + kk * 32 + ((lane >> 4) << 3);
        uint4 wv = *(const uint4*)((const char*)w3f + (size_t)i * 16);
        const float* cb = &ca_s[c0];
        uint4 ov;
        {
            float lo = __uint_as_float(wv.x << 16), hi = __uint_as_float(wv.x & 0xffff0000u);
            ov.x = f2bf(lo * cb[0]) | (f2bf(hi * cb[1]) << 16);
        }
        {
            float lo = __uint_as_float(wv.y << 16), hi = __uint_as_float(wv.y & 0xffff0000u);
            ov.y = f2bf(lo * cb[2]) | (f2bf(hi * cb[3]) << 16);
        }
        {
            float lo = __uint_as_float(wv.z << 16), hi = __uint_as_float(wv.z & 0xffff0000u);
            ov.z = f2bf(lo * cb[4]) | (f2bf(hi * cb[5]) << 16);
        }
        {
            float lo = __uint_as_float(wv.w << 16), hi = __uint_as_float(wv.w & 0xffff0000u);
            ov.w = f2bf(lo * cb[6]) | (f2bf(hi * cb[7]) << 16);
        }
        *(uint4*)((char*)w3b + ((size_t)b * 8192 + i) * 16) = ov;
    }
}

// ---------------------------------------------------------------------------
// k_gemm: per (b, 128-col n-tile), 512 threads / 8 waves — GEMM + sa ONLY:
//   h2[128 o][128 n] = w3b[b] @ x  over c=512  (ca pre-folded into w3b)
//   sa[b][n] = sigmoid(sum_o w4[o]*relu(h2+bias2) + b4)
// Read-only x (column-tiled); writes just 128 floats/block.
// x staged via 2-deep reg prefetch -> bf16 -> swizzled LDS dbuf;
// A-frags direct from global w3b (L2-hot, lane-pre-ordered);
// one lgkm-only barrier per chunk (vmcnt never drained in-loop).
// ---------------------------------------------------------------------------
__global__ __launch_bounds__(512, 2) void k_gemm(
    const float* __restrict__ x, const unsigned short* __restrict__ w3b,
    const float* __restrict__ bias2, const float* __restrict__ w4,
    const float* __restrict__ b4, float* __restrict__ sa)
{
    __shared__ __align__(16) short lds_x[2][NT * KC];   // 2 x 16 KB, swizzled [n][c]
    __shared__ float red[4][NT];
    __shared__ float bias2_s[CR];
    __shared__ float w4_s[CR];

    const int t    = threadIdx.x;
    const int lane = t & 63;
    const int w    = t >> 6;           // 0..7
    const int b    = blockIdx.y;
    const int n0   = blockIdx.x * NT;
    const int wo   = (w & 3) * 32;     // wave o-base
    const int wn   = (w >> 2) * 64;    // wave n-base
    const int ob0  = (w & 3) * 2;

    const size_t xbase = (size_t)b * C * N + n0;
    const int ng = t & 63;   // x-stage: n pair = 2*ng  (128 n)
    const int cg = t >> 6;   // x-stage: c sub  = cg*8

    if (t < CR) { bias2_s[t] = bias2[t]; w4_s[t] = w4[t]; }

    float2 xva[8], xvb[8];

#define LOADX(dst, CK) do { const int c0_ = (CK) * KC;                         \
    _Pragma("unroll") for (int ci = 0; ci < 8; ++ci)                           \
        dst[ci] = *(const float2*)(x + xbase + (size_t)(c0_ + cg * 8 + ci) * N + 2 * ng); \
} while (0)

#define CONVERT_WRITE(src, BUF) do {                                           \
    unsigned q0[4], q1[4];                                                     \
    _Pragma("unroll") for (int h = 0; h < 4; ++h) {                            \
        q0[h] = f2bf(src[2 * h].x) | (f2bf(src[2 * h + 1].x) << 16);           \
        q1[h] = f2bf(src[2 * h].y) | (f2bf(src[2 * h + 1].y) << 16);           \
    }                                                                          \
    int nl0 = 2 * ng, nl1 = 2 * ng + 1;                                        \
    int a0 = (nl0 * 128 + cg * 16) ^ ((nl0 & 7) << 4);                         \
    int a1 = (nl1 * 128 + cg * 16) ^ ((nl1 & 7) << 4);                         \
    *(uint4*)((char*)lds_x[BUF] + a0) = make_uint4(q0[0], q0[1], q0[2], q0[3]);\
    *(uint4*)((char*)lds_x[BUF] + a1) = make_uint4(q1[0], q1[1], q1[2], q1[3]);\
} while (0)

    LOADX(xva, 0);
    LOADX(xvb, 1);
    CONVERT_WRITE(xva, 0);          // chunk 0 -> buf 0 (vmcnt wait by compiler)

    f32x4 acc[2][4];
    #pragma unroll
    for (int i = 0; i < 2; ++i)
        #pragma unroll
        for (int j = 0; j < 4; ++j) acc[i][j] = (f32x4)0.f;

    const char* wb = (const char*)w3b + (size_t)b * 131072;

    #pragma unroll
    for (int ck = 0; ck < 8; ++ck) {
        if (ck < 6) { if (ck & 1) LOADX(xvb, ck + 2); else LOADX(xva, ck + 2); }

        LGKM_BARRIER();             // buf(ck&1) visible; prefetch NOT drained

        #pragma unroll
        for (int kk = 0; kk < 2; ++kk) {
            bf16x8 af[2];
            #pragma unroll
            for (int i = 0; i < 2; ++i) {
                int g = ck * 16 + kk * 8 + ob0 + i;
                af[i] = *(const bf16x8*)(wb + (size_t)(g * 64 + lane) * 16);
            }
            bf16x8 bfr[4];
            #pragma unroll
            for (int j = 0; j < 4; ++j) {
                int br = wn + j * 16 + (lane & 15);
                int bb = (br * 128 + kk * 64 + (lane >> 4) * 16) ^ ((br & 7) << 4);
                bfr[j] = *(const bf16x8*)((const char*)lds_x[ck & 1] + bb);
            }
            #pragma unroll
            for (int i = 0; i < 2; ++i)
                #pragma unroll
                for (int j = 0; j < 4; ++j)
                    acc[i][j] = __builtin_amdgcn_mfma_f32_16x16x32_bf16(af[i], bfr[j], acc[i][j], 0, 0, 0);
        }
        if (ck < 7) { if (ck & 1) CONVERT_WRITE(xva, 0); else CONVERT_WRITE(xvb, 1); }
    }

    // ---- sa: per-lane partial over this wave's 32 o's, then cross-lane.
    // C/D layout: col = lane&15 (n), row = (lane>>4)*4 + reg (o)
    #pragma unroll
    for (int j = 0; j < 4; ++j) {
        float p = 0.f;
        #pragma unroll
        for (int i = 0; i < 2; ++i) {
            #pragma unroll
            for (int r = 0; r < 4; ++r) {
                int o = wo + i * 16 + ((lane >> 4) << 2) + r;
                p = fmaf(w4_s[o], fmaxf(acc[i][j][r] + bias2_s[o], 0.f), p);
            }
        }
        p += __shfl_xor(p, 16, 64);
        p += __shfl_xor(p, 32, 64);
        if (lane < 16) red[w & 3][wn + j * 16 + lane] = p;
    }
    __syncthreads();
    if (t < NT)
        sa[b * N + n0 + t] = sigmoidf_(red[0][t] + red[1][t] + red[2][t] + red[3][t] + b4[0]);
#undef LOADX
#undef CONVERT_WRITE
}

// ---------------------------------------------------------------------------
// k_out: pure streaming epilogue, fully contiguous (fill-kernel shape):
//   out[b][c][n] = x * (1 + ca[b][c] * sa[b][n])
// 2048 blocks x 256 threads, 16 float4/thread; each iteration is a
// contiguous 32 MB sweep.  sa/ca reads are L1/L2-hit.
// ---------------------------------------------------------------------------
__global__ __launch_bounds__(256) void k_out(
    const float* __restrict__ x, const float* __restrict__ ca,
    const float* __restrict__ sa, float* __restrict__ out)
{
    const float4* x4  = (const float4*)x;
    const float4* sa4 = (const float4*)sa;
    float4* o4        = (float4*)out;
    int base = blockIdx.x * 256 + threadIdx.x;
    #pragma unroll 4
    for (int it = 0; it < 16; ++it) {
        int i4 = base + it * 524288;       // 0 .. 8388607, contiguous per it
        float4 v  = x4[i4];
        int b  = i4 >> 19;
        int c  = (i4 >> 10) & 511;
        int n4 = i4 & 1023;
        float cav = ca[b * 512 + c];
        float4 sv = sa4[b * 1024 + n4];
        float4 r;
        r.x = v.x * fmaf(cav, sv.x, 1.0f);
        r.y = v.y * fmaf(cav, sv.y, 1.0f);
        r.z = v.z * fmaf(cav, sv.z, 1.0f);
        r.w = v.w * fmaf(cav, sv.w, 1.0f);
        o4[i4] = r;
    }
}

extern "C" void kernel_launch(void* const* d_in, const int* in_sizes, int n_in,
                              void* d_out, int out_size, void* d_ws, size_t ws_size,
                              hipStream_t stream)
{
    const float* x   = (const float*)d_in[0];
    const float* w1  = (const float*)d_in[1];
    const float* b1  = (const float*)d_in[2];
    const float* w2  = (const float*)d_in[3];
    const float* b2  = (const float*)d_in[4];
    const float* w3  = (const float*)d_in[5];
    const float* b3  = (const float*)d_in[6];
    const float* g   = (const float*)d_in[7];
    const float* be  = (const float*)d_in[8];
    const float* mn  = (const float*)d_in[9];
    const float* vr  = (const float*)d_in[10];
    const float* w4  = (const float*)d_in[11];
    const float* b4  = (const float*)d_in[12];
    float* out = (float*)d_out;

    float* ws     = (float*)d_ws;
    float* pooled = ws;                                   // 8192 floats
    float* ca     = ws + 8192;                            // 8192 floats
    float* bias2  = ws + 16384;                           // 128 floats (+pad)
    unsigned short* w3f = (unsigned short*)(ws + 16640);  // 128 KB
    unsigned short* w3b = (unsigned short*)(ws + 49408);  // 2 MB
    float* sa     = ws + 573696;                          // 16*4096 floats

    k_pre<<<2048 + 32, 256, 0, stream>>>(x, pooled, w3, b3, g, be, mn, vr, w3f, bias2);
    k_ca<<<B, 256, 0, stream>>>(pooled, w1, b1, w2, b2, w3f, ca, w3b);
    dim3 g3(N / NT, B);
    k_gemm<<<g3, 512, 0, stream>>>(x, w3b, bias2, w4, b4, sa);
    k_out<<<2048, 256, 0, stream>>>(x, ca, sa, out);
}